// Round 4
// baseline (512.559 us; speedup 1.0000x reference)
//
#include <hip/hip_runtime.h>
#include <hip/hip_bf16.h>
#include <hip/hip_cooperative_groups.h>
#include <math.h>

namespace cg = cooperative_groups;

#define BN 1024
#define DIN 64
#define HD 128
#define EN 8192

typedef unsigned long long u64;

struct Params {
    const float* mu; const int* ei;
    const float* W1; const float* b1; const float* W2; const float* b2;
    const float* Ws1; const float* bs1; const float* Ws2; const float* bs2;
    const float* Wg1; const float* bg1; const float* Wg2; const float* bg2;
    float* out; char* ws;
};

struct SmemT {
    union {
        struct { float As[64][68]; float Cs[64][68]; float w2[HD]; } sc;   // 35 KB
        struct { int pa[BN]; int pb[BN]; } mg;                              // 8 KB
        struct { float xr[4][HD]; } mm;                                     // 2 KB
        struct { float hp[2 * HD]; float z1[HD]; } gm;                      // 1.5 KB
    } u;
};

__device__ __forceinline__ u64 edge_key(float w, int i, int j) {
    unsigned u = __float_as_uint(w);
    u = (u & 0x80000000u) ? ~u : (u | 0x80000000u);
    int a = i < j ? i : j, b = i < j ? j : i;
    unsigned packed = (unsigned)(a * BN + b);
    return ((u64)u << 20) | (u64)(0xFFFFFu - packed);
}

// out[r0..r0+3][col] = sum_k x[row][k]*W[k][col] (+bias) ; chain order = k ascending
__device__ void mm_phase(SmemT& sm, int tid, int bid, const float* x, const float* W,
                         const float* bias, float* out, int K) {
    int r0 = bid * 4;
    for (int idx = tid; idx < 4 * K; idx += 256)
        sm.u.mm.xr[idx / K][idx % K] = x[(r0 + idx / K) * K + idx % K];
    __syncthreads();
    int col = tid & 127;
    int ra = tid >> 7;  // rows ra and ra+2
    float b = bias ? bias[col] : 0.0f;
    float a0 = b, a1 = b;
    for (int k = 0; k < K; k++) {
        float w = W[k * HD + col];
        a0 = fmaf(sm.u.mm.xr[ra][k], w, a0);
        a1 = fmaf(sm.u.mm.xr[ra + 2][k], w, a1);
    }
    out[(r0 + ra) * HD + col] = a0;
    out[(r0 + ra + 2) * HD + col] = a1;
}

__device__ void gather_phase(int tid, int bid, const float* xwv, const float* bvec,
                             const int* src, const int* slots, const int* cnt,
                             const float* dinv, float* hout) {
    int t = tid & 127;
    for (int p = 0; p < 2; p++) {
        int d = bid * 4 + (tid >> 7) + p * 2;
        float dd = dinv[d];
        float acc = 0.0f;
        int base = d * 64, n = cnt[d];
        if (n > 64) n = 64;
        for (int s = 0; s < n; s++) {
            int e = slots[base + s];
            int sn = src[e];
            acc = fmaf(xwv[sn * HD + t], dinv[sn] * dd, acc);
        }
        acc = fmaf(xwv[d * HD + t], dd * dd, acc);
        acc += bvec[t];
        hout[d * HD + t] = fmaxf(acc, 0.0f);
    }
}

__device__ void merge_block(SmemT& sm, int tid, int* comp, u64* best, u64* mst, int* mstcnt) {
    int* pa = sm.u.mg.pa;
    int* pb = sm.u.mg.pb;
    for (int c = tid; c < BN; c += 256) {
        int myComp = comp[c];
        bool root = (myComp == c);
        u64 e = best[c];
        int t = c;
        if (root && e) {
            unsigned packed = 0xFFFFFu - (unsigned)(e & 0xFFFFFu);
            int a = packed >> 10, b = packed & 1023;
            int ca = comp[a], cb = comp[b];
            t = (ca == c) ? cb : ca;
        }
        pa[c] = (root && e) ? t : c;
    }
    __syncthreads();
    for (int c = tid; c < BN; c += 256) {
        int myComp = comp[c];
        bool root = (myComp == c);
        u64 e = best[c];
        int p0 = pa[c];
        if (root && e) {
            int t = pa[c];
            bool mutual = (pa[t] == c);
            if (mutual && c < t) p0 = c;
            if (!(mutual && c > t)) {
                int idx = atomicAdd(mstcnt, 1);
                mst[idx] = e;
            }
        }
        pb[c] = p0;
    }
    __syncthreads();
    for (int c = tid; c < BN; c += 256) pa[c] = pb[c];
    __syncthreads();
    for (int it = 0; it < 10; it++) {
        for (int c = tid; c < BN; c += 256) pb[c] = pa[pa[c]];
        __syncthreads();
        for (int c = tid; c < BN; c += 256) pa[c] = pb[c];
        __syncthreads();
    }
    for (int c = tid; c < BN; c += 256) {
        comp[c] = pa[comp[c]];
        best[c] = 0ull;
    }
}

__global__ __launch_bounds__(256) void k_mega(Params P) {
    cg::grid_group grid = cg::this_grid();
    const int tid = threadIdx.x;
    const int bid = blockIdx.x;
    const int gid = bid * 256 + tid;
    __shared__ SmemT sm;

    char* ws = P.ws;
    int*   slots = (int*)ws;                         // dies after gather2, aliased by S
    int*   cnt   = (int*)(ws + 262144);
    float* dinv  = (float*)(ws + 266240);
    float* S     = (float*)ws;                       // 4 MiB, born at scores
    float* xw    = (float*)(ws + 4194304);
    float* h1    = (float*)(ws + 4718592);
    float* h2    = (float*)(ws + 5242880);
    float* Aa    = (float*)(ws + 5767168);
    float* Cc    = (float*)(ws + 6291456);
    int*   comp  = (int*)(ws + 6815744);
    u64*   best  = (u64*)(ws + 6819840);
    u64*   mst   = (u64*)(ws + 6828032);
    int*   mstcnt = (int*)(ws + 6836224);
    int*   pairs  = (int*)(ws + 6840320);

    const int* src = P.ei;
    const int* dst = P.ei + EN;

    // ---- phase 0: init ----
    if (gid < BN) { cnt[gid] = 0; comp[gid] = gid; best[gid] = 0ull; }
    if (gid == 0) *mstcnt = 0;
    grid.sync();

    // ---- phase 1: bucket fill (order nondet, fixed below) ----
    if (gid < EN) {
        int d = dst[gid];
        int p = atomicAdd(&cnt[d], 1);
        if (p < 64) slots[d * 64 + p] = gid;
    }
    grid.sync();

    // ---- phase 2: per-node bucket sort by edge id + dinv ----
    if (gid < BN) {
        int n = cnt[gid];
        if (n > 64) n = 64;
        int b = gid * 64;
        for (int k = 1; k < n; k++) {
            int v = slots[b + k];
            int q = k - 1;
            while (q >= 0 && slots[b + q] > v) { slots[b + q + 1] = slots[b + q]; q--; }
            slots[b + q + 1] = v;
        }
        dinv[gid] = 1.0f / sqrtf(fmaxf((float)(n + 1), 1e-12f));
    }
    grid.sync();

    // ---- GCN layer 1 ----
    mm_phase(sm, tid, bid, P.mu, P.W1, nullptr, xw, DIN);
    grid.sync();
    gather_phase(tid, bid, xw, P.b1, src, slots, cnt, dinv, h1);
    grid.sync();
    // ---- GCN layer 2 ----
    mm_phase(sm, tid, bid, h1, P.W2, nullptr, xw, HD);
    grid.sync();
    gather_phase(tid, bid, xw, P.b2, src, slots, cnt, dinv, h2);
    grid.sync();

    // ---- Aa = h2@Ws1[:H], Cc = h2@Ws1[H:]+bs1 ----
    {
        int r0 = bid * 4;
        for (int idx = tid; idx < 4 * HD; idx += 256)
            sm.u.mm.xr[idx / HD][idx % HD] = h2[(r0 + idx / HD) * HD + idx % HD];
        __syncthreads();
        int col = tid & 127;
        int ra = tid >> 7;
        float bc = P.bs1[col];
        float aA0 = 0.0f, aA1 = 0.0f, aC0 = bc, aC1 = bc;
        for (int k = 0; k < HD; k++) {
            float wa = P.Ws1[k * HD + col];
            float wc = P.Ws1[(HD + k) * HD + col];
            aA0 = fmaf(sm.u.mm.xr[ra][k], wa, aA0);
            aA1 = fmaf(sm.u.mm.xr[ra + 2][k], wa, aA1);
            aC0 = fmaf(sm.u.mm.xr[ra][k], wc, aC0);
            aC1 = fmaf(sm.u.mm.xr[ra + 2][k], wc, aC1);
        }
        Aa[(r0 + ra) * HD + col] = aA0;
        Aa[(r0 + ra + 2) * HD + col] = aA1;
        Cc[(r0 + ra) * HD + col] = aC0;
        Cc[(r0 + ra + 2) * HD + col] = aC1;
    }
    grid.sync();

    // ---- scores (exact same per-output fma order as before) ----
    if (bid < 136) {
        int bi = 0, rem = bid;
        while (rem >= 16 - bi) { rem -= 16 - bi; bi++; }
        int bj = bi + rem;
        int R = bi * 64, Cb = bj * 64;
        if (tid < HD) sm.u.sc.w2[tid] = P.Ws2[tid];
        int tx = tid & 15, ty = tid >> 4;
        float acc[4][4] = {};
        for (int half = 0; half < 2; half++) {
            int k0 = half * 64;
            __syncthreads();
            for (int idx = tid; idx < 64 * 64; idx += 256) {
                int row = idx >> 6;
                int kk = idx & 63;
                sm.u.sc.As[kk][row] = Aa[(R + row) * HD + k0 + kk];
                sm.u.sc.Cs[kk][row] = Cc[(Cb + row) * HD + k0 + kk];
            }
            __syncthreads();
            for (int kk = 0; kk < 64; kk++) {
                float4 av = *(const float4*)&sm.u.sc.As[kk][ty * 4];
                float4 cv = *(const float4*)&sm.u.sc.Cs[kk][tx * 4];
                float wk = sm.u.sc.w2[k0 + kk];
                float ar[4] = {av.x, av.y, av.z, av.w};
                float cr[4] = {cv.x, cv.y, cv.z, cv.w};
#pragma unroll
                for (int r = 0; r < 4; r++)
#pragma unroll
                    for (int q = 0; q < 4; q++) {
                        float tv = fmaxf(ar[r] + cr[q], 0.0f);
                        acc[r][q] = fmaf(tv, wk, acc[r][q]);
                    }
            }
        }
        float b2 = P.bs2[0];
#pragma unroll
        for (int r = 0; r < 4; r++)
#pragma unroll
            for (int q = 0; q < 4; q++) {
                int gr = R + ty * 4 + r, gc = Cb + tx * 4 + q;
                float v = acc[r][q] + b2;
                if (gr < gc) { S[gr * BN + gc] = v; S[gc * BN + gr] = v; }
                else if (gr == gc) S[gr * BN + gc] = 0.0f;
            }
    }
    grid.sync();

    // ---- Boruvka rounds (uniform break on convergence) ----
    for (int r = 0; r < 10; r++) {
        if (*(volatile int*)mstcnt >= BN - 1) break;  // uniform (read post-sync)
        {
            int i = gid >> 6, lane = gid & 63;
            int ci = comp[i];
            u64 loc = 0ull;
            const float* Srow = S + i * BN;
            for (int j = lane; j < BN; j += 64)
                if (comp[j] != ci) {
                    u64 key = edge_key(Srow[j], i, j);
                    if (key > loc) loc = key;
                }
            for (int off = 32; off > 0; off >>= 1) {
                u64 o = __shfl_xor(loc, off);
                if (o > loc) loc = o;
            }
            if (lane == 0 && loc) atomicMax(&best[ci], loc);
        }
        grid.sync();
        if (bid == 0) merge_block(sm, tid, comp, best, mst, mstcnt);
        grid.sync();
    }

    // ---- rank & emit edge index (keys unique -> bijective ranks) ----
    {
        int e = gid >> 6, lane = gid & 63;
        if (e < BN - 1) {
            u64 mykey = mst[e];
            int cg_ = 0;
            for (int f = lane; f < BN - 1; f += 64) cg_ += (mst[f] > mykey) ? 1 : 0;
            for (int off = 32; off > 0; off >>= 1) cg_ += __shfl_xor(cg_, off);
            if (lane == 0) {
                int rk = cg_;
                unsigned packed = 0xFFFFFu - (unsigned)(mykey & 0xFFFFFu);
                int i = packed >> 10, j2 = packed & 1023;
                P.out[2 * rk] = (float)i;
                P.out[2 * rk + 1] = (float)j2;
                P.out[2046 + 2 * rk] = (float)j2;
                P.out[2046 + 2 * rk + 1] = (float)i;
                pairs[2 * rk] = i;
                pairs[2 * rk + 1] = j2;
            }
        }
    }
    grid.sync();

    // ---- gamma MLP over sorted MST edges ----
    for (int e = bid; e < BN - 1; e += 256) {
        int i = pairs[2 * e], j = pairs[2 * e + 1];
        sm.u.gm.hp[tid] = (tid < HD) ? h2[i * HD + tid] : h2[j * HD + (tid - HD)];
        __syncthreads();
        if (tid < HD) {
            float acc = P.bg1[tid];
            for (int k = 0; k < 2 * HD; k++) acc = fmaf(sm.u.gm.hp[k], P.Wg1[k * HD + tid], acc);
            sm.u.gm.z1[tid] = fmaxf(acc, 0.0f);
        }
        __syncthreads();
        if (tid < DIN) {
            float g = P.bg2[tid];
            for (int k = 0; k < HD; k++) g = fmaf(sm.u.gm.z1[k], P.Wg2[k * DIN + tid], g);
            P.out[4092 + e * DIN + tid] = tanhf(g);
        }
        __syncthreads();
    }
}

extern "C" void kernel_launch(void* const* d_in, const int* in_sizes, int n_in,
                              void* d_out, int out_size, void* d_ws, size_t ws_size,
                              hipStream_t stream) {
    Params P;
    P.mu  = (const float*)d_in[0];
    P.ei  = (const int*)d_in[1];
    P.W1  = (const float*)d_in[2];
    P.b1  = (const float*)d_in[3];
    P.W2  = (const float*)d_in[4];
    P.b2  = (const float*)d_in[5];
    P.Ws1 = (const float*)d_in[6];
    P.bs1 = (const float*)d_in[7];
    P.Ws2 = (const float*)d_in[8];
    P.bs2 = (const float*)d_in[9];
    P.Wg1 = (const float*)d_in[10];
    P.bg1 = (const float*)d_in[11];
    P.Wg2 = (const float*)d_in[12];
    P.bg2 = (const float*)d_in[13];
    P.out = (float*)d_out;
    P.ws  = (char*)d_ws;

    void* args[] = { &P };
    hipLaunchCooperativeKernel((const void*)k_mega, dim3(256), dim3(256), args, 0, stream);
}

// Round 5
// 190.199 us; speedup vs baseline: 2.6949x; 2.6949x over previous
//
#include <hip/hip_runtime.h>
#include <hip/hip_bf16.h>
#include <math.h>

#define BN 1024
#define DIN 64
#define HD 128
#define EN 8192
#define SLOTS_STRIDE 64
#define MMR 8

typedef unsigned long long u64;

// ---------------- init ----------------
__global__ void k_init(int* cnt, int* comp, u64* best, int* mstcnt) {
    int i = blockIdx.x * blockDim.x + threadIdx.x;
    if (i < BN) { cnt[i] = 0; comp[i] = i; best[i] = 0ull; }
    if (i == 0) *mstcnt = 0;
}

// atomic bucket fill (order nondeterministic; fixed by k_finish sort)
__global__ void k_fill(const int* dst, int* cnt, int* slots) {
    int e = blockIdx.x * blockDim.x + threadIdx.x;
    if (e < EN) {
        int d = dst[e];
        int p = atomicAdd(&cnt[d], 1);
        if (p < SLOTS_STRIDE) slots[d * SLOTS_STRIDE + p] = e;
    }
}

// per-node insertion sort by edge id -> deterministic CSR order; also dinv
__global__ __launch_bounds__(128) void k_finish(int* slots, const int* cnt, float* dinv) {
    __shared__ int buf[128][65];
    int tid = threadIdx.x;
    int t = blockIdx.x * 128 + tid;
    int n = cnt[t];
    if (n > SLOTS_STRIDE) n = SLOTS_STRIDE;
    for (int k = 0; k < n; k++) buf[tid][k] = slots[t * SLOTS_STRIDE + k];
    for (int k = 1; k < n; k++) {
        int v = buf[tid][k];
        int q = k - 1;
        while (q >= 0 && buf[tid][q] > v) { buf[tid][q + 1] = buf[tid][q]; q--; }
        buf[tid][q + 1] = v;
    }
    for (int k = 0; k < n; k++) slots[t * SLOTS_STRIDE + k] = buf[tid][k];
    dinv[t] = 1.0f / sqrtf(fmaxf((float)(n + 1), 1e-12f));
}

// out[r0..r0+7][col] = sum_k x[row][k]*W[k][col] (+ bias[col]) — 8 rows/block
__global__ __launch_bounds__(128) void k_mm8(const float* x, const float* W, const float* bias,
                                             float* out, int K) {
    __shared__ float xr[MMR][HD];
    int col = threadIdx.x;
    int r0 = blockIdx.x * MMR;
#pragma unroll
    for (int r = 0; r < MMR; r++)
        if (col < K) xr[r][col] = x[(r0 + r) * K + col];
    __syncthreads();
    float b = bias ? bias[col] : 0.0f;
    float acc[MMR];
#pragma unroll
    for (int r = 0; r < MMR; r++) acc[r] = b;
#pragma unroll 4
    for (int k = 0; k < K; k++) {
        float w = W[k * HD + col];
#pragma unroll
        for (int r = 0; r < MMR; r++) acc[r] = fmaf(xr[r][k], w, acc[r]);
    }
#pragma unroll
    for (int r = 0; r < MMR; r++) out[(r0 + r) * HD + col] = acc[r];
}

// fused: Aa = h@Ws1[:H], Cc = h@Ws1[H:] + bs1 — 8 rows/block
__global__ __launch_bounds__(128) void k_mmAC(const float* h, const float* Ws1, const float* bs1,
                                              float* Aa, float* Cc) {
    __shared__ float xr[MMR][HD];
    int col = threadIdx.x;
    int r0 = blockIdx.x * MMR;
#pragma unroll
    for (int r = 0; r < MMR; r++) xr[r][col] = h[(r0 + r) * HD + col];
    __syncthreads();
    float accA[MMR], accC[MMR];
    float bc = bs1[col];
#pragma unroll
    for (int r = 0; r < MMR; r++) { accA[r] = 0.0f; accC[r] = bc; }
#pragma unroll 2
    for (int k = 0; k < HD; k++) {
        float wa = Ws1[k * HD + col];
        float wc = Ws1[(HD + k) * HD + col];
#pragma unroll
        for (int r = 0; r < MMR; r++) {
            accA[r] = fmaf(xr[r][k], wa, accA[r]);
            accC[r] = fmaf(xr[r][k], wc, accC[r]);
        }
    }
#pragma unroll
    for (int r = 0; r < MMR; r++) {
        Aa[(r0 + r) * HD + col] = accA[r];
        Cc[(r0 + r) * HD + col] = accC[r];
    }
}

// GCN gather: out[d][t] = relu( sum_edges xw[src]*dinv[src]*dinv[d] + xw[d]*dinv[d]^2 + b[t] )
__global__ __launch_bounds__(128) void k_gather(const float* xw, const float* bvec, const int* src,
                                                const int* slots, const int* cnt,
                                                const float* dinv, float* hout) {
    int d = blockIdx.x, t = threadIdx.x;
    float dd = dinv[d];
    float acc = 0.0f;
    int base = d * SLOTS_STRIDE, n = cnt[d];
    if (n > SLOTS_STRIDE) n = SLOTS_STRIDE;
    for (int s = 0; s < n; s++) {
        int e = slots[base + s];
        int sn = src[e];
        acc = fmaf(xw[sn * HD + t], dinv[sn] * dd, acc);
    }
    acc = fmaf(xw[d * HD + t], dd * dd, acc);
    acc += bvec[t];
    hout[d * HD + t] = fmaxf(acc, 0.0f);
}

// scores: S[i][j] = S[j][i] = sum_k relu(A[min][k]+C[max][k])*w2[k] + bs2, diag 0
__global__ __launch_bounds__(256) void k_scores(const float* Aa, const float* Cc,
                                                const float* Ws2, const float* bs2v, float* S) {
    int bi = blockIdx.y, bj = blockIdx.x;
    if (bi > bj) return;
    __shared__ float As[64][68];
    __shared__ float Cs[64][68];
    __shared__ float w2[HD];
    int tid = threadIdx.x;
    int R = bi * 64, Cb = bj * 64;
    if (tid < HD) w2[tid] = Ws2[tid];
    int tx = tid & 15, ty = tid >> 4;
    float acc[4][4] = {};
    for (int half = 0; half < 2; half++) {
        int k0 = half * 64;
        __syncthreads();
        for (int idx = tid; idx < 64 * 64; idx += 256) {
            int row = idx >> 6;
            int kk = idx & 63;
            As[kk][row] = Aa[(R + row) * HD + k0 + kk];
            Cs[kk][row] = Cc[(Cb + row) * HD + k0 + kk];
        }
        __syncthreads();
        for (int kk = 0; kk < 64; kk++) {
            float4 av = *(const float4*)&As[kk][ty * 4];
            float4 cv = *(const float4*)&Cs[kk][tx * 4];
            float wk = w2[k0 + kk];
            float ar[4] = {av.x, av.y, av.z, av.w};
            float cr[4] = {cv.x, cv.y, cv.z, cv.w};
#pragma unroll
            for (int r = 0; r < 4; r++)
#pragma unroll
                for (int q = 0; q < 4; q++) {
                    float tv = fmaxf(ar[r] + cr[q], 0.0f);
                    acc[r][q] = fmaf(tv, wk, acc[r][q]);
                }
        }
    }
    float b2 = bs2v[0];
#pragma unroll
    for (int r = 0; r < 4; r++)
#pragma unroll
        for (int q = 0; q < 4; q++) {
            int gr = R + ty * 4 + r, gc = Cb + tx * 4 + q;
            float v = acc[r][q] + b2;
            if (gr < gc) { S[gr * BN + gc] = v; S[gc * BN + gr] = v; }
            else if (gr == gc) S[gr * BN + gc] = 0.0f;
        }
}

__device__ __forceinline__ u64 edge_key(float w, int i, int j) {
    unsigned u = __float_as_uint(w);
    u = (u & 0x80000000u) ? ~u : (u | 0x80000000u);
    int a = i < j ? i : j, b = i < j ? j : i;
    unsigned packed = (unsigned)(a * BN + b);
    return ((u64)u << 20) | (u64)(0xFFFFFu - packed);
}

// wave-per-row best-outgoing-edge scan; early-exit when MST complete
__global__ __launch_bounds__(256) void k_best(const float* S, const int* comp,
                                              u64* best, const int* mstcnt) {
    if (*mstcnt >= BN - 1) return;
    int lane = threadIdx.x & 63;
    int i = blockIdx.x * 4 + (threadIdx.x >> 6);
    int ci = comp[i];
    const float* Srow = S + (size_t)i * BN;
    u64 loc = 0ull;
    for (int j = lane; j < BN; j += 64)
        if (comp[j] != ci) {
            u64 key = edge_key(Srow[j], i, j);
            if (key > loc) loc = key;
        }
#pragma unroll
    for (int off = 32; off > 0; off >>= 1) {
        u64 o = __shfl_xor(loc, off);
        if (o > loc) loc = o;
    }
    if (lane == 0 && loc) atomicMax(&best[ci], loc);
}

// merge + (on the converging round) rank-and-emit finale
__global__ __launch_bounds__(1024) void k_merge(int* comp, u64* best, u64* mst, int* mstcnt,
                                                float* out, int* pairs) {
    __shared__ int pa[BN], pb[BN];
    __shared__ u64 sk[BN];
    int c = threadIdx.x;
    if (*mstcnt >= BN - 1) return;
    int myComp = comp[c];
    bool root = (myComp == c);
    u64 e = best[c];
    int t = c;
    if (root && e) {
        unsigned packed = 0xFFFFFu - (unsigned)(e & 0xFFFFFu);
        int a = packed >> 10, b = packed & 1023;
        int ca = comp[a], cb = comp[b];
        t = (ca == c) ? cb : ca;
    }
    pa[c] = (root && e) ? t : c;
    __syncthreads();
    bool mutual = root && e && (pa[t] == c);
    int p0 = pa[c];
    if (mutual && c < t) p0 = c;
    __syncthreads();
    pa[c] = p0;
    __syncthreads();
    if (root && e && !(mutual && c > t)) {
        int idx = atomicAdd(mstcnt, 1);
        mst[idx] = e;
    }
    for (int it = 0; it < 10; it++) {
        pb[c] = pa[pa[c]];
        __syncthreads();
        pa[c] = pb[c];
        __syncthreads();
    }
    comp[c] = pa[myComp];
    best[c] = 0ull;
    __syncthreads();
    // finale: first round that completes the MST emits sorted outputs
    if (*mstcnt == BN - 1) {
        sk[c] = (c < BN - 1) ? mst[c] : 0ull;
        __syncthreads();
        if (c < BN - 1) {
            u64 mykey = sk[c];
            int rk = 0;
            for (int f = 0; f < BN - 1; f++) rk += (sk[f] > mykey) ? 1 : 0;
            unsigned packed = 0xFFFFFu - (unsigned)(mykey & 0xFFFFFu);
            int i = packed >> 10, j2 = packed & 1023;
            out[2 * rk] = (float)i;
            out[2 * rk + 1] = (float)j2;
            out[2046 + 2 * rk] = (float)j2;
            out[2046 + 2 * rk + 1] = (float)i;
            pairs[2 * rk] = i;
            pairs[2 * rk + 1] = j2;
        }
    }
}

__global__ __launch_bounds__(128) void k_gamma(const float* h, const int* pairs,
                                               const float* Wg1, const float* bg1,
                                               const float* Wg2, const float* bg2, float* out) {
    int eidx = blockIdx.x;
    __shared__ float hp[2 * HD];
    __shared__ float z1[HD];
    int t = threadIdx.x;
    int i = pairs[2 * eidx], j = pairs[2 * eidx + 1];
    hp[t] = h[i * HD + t];
    hp[HD + t] = h[j * HD + t];
    __syncthreads();
    float acc = bg1[t];
    for (int k = 0; k < 2 * HD; k++) acc = fmaf(hp[k], Wg1[k * HD + t], acc);
    z1[t] = fmaxf(acc, 0.0f);
    __syncthreads();
    if (t < DIN) {
        float g = bg2[t];
        for (int k = 0; k < HD; k++) g = fmaf(z1[k], Wg2[k * DIN + t], g);
        out[4092 + eidx * DIN + t] = tanhf(g);
    }
}

extern "C" void kernel_launch(void* const* d_in, const int* in_sizes, int n_in,
                              void* d_out, int out_size, void* d_ws, size_t ws_size,
                              hipStream_t stream) {
    const float* mu  = (const float*)d_in[0];
    const int*   ei  = (const int*)d_in[1];
    const float* W1  = (const float*)d_in[2];
    const float* b1  = (const float*)d_in[3];
    const float* W2  = (const float*)d_in[4];
    const float* b2  = (const float*)d_in[5];
    const float* Ws1 = (const float*)d_in[6];
    const float* bs1 = (const float*)d_in[7];
    const float* Ws2 = (const float*)d_in[8];
    const float* bs2 = (const float*)d_in[9];
    const float* Wg1 = (const float*)d_in[10];
    const float* bg1 = (const float*)d_in[11];
    const float* Wg2 = (const float*)d_in[12];
    const float* bg2 = (const float*)d_in[13];
    float* out = (float*)d_out;

    const int* src = ei;
    const int* dst = ei + EN;

    char* ws = (char*)d_ws;
    // Phase-1 arrays (dead before k_scores) alias the S region:
    int*   slots = (int*)(ws);                      // 256 KiB, dies after gather2
    int*   cnt   = (int*)(ws + 262144);             // 4 KiB, dies after gather2
    float* dinv  = (float*)(ws + 266240);           // 4 KiB, dies after gather2
    float* S     = (float*)(ws);                    // 4 MiB, born at k_scores
    float* xw    = (float*)(ws + 4194304);          // 512 KiB
    float* h1    = (float*)(ws + 4718592);          // 512 KiB
    float* h2    = (float*)(ws + 5242880);          // 512 KiB (live until gamma)
    float* Aa    = (float*)(ws + 5767168);          // 512 KiB
    float* Cc    = (float*)(ws + 6291456);          // 512 KiB
    int*   comp  = (int*)(ws + 6815744);            // 4 KiB
    u64*   best  = (u64*)(ws + 6819840);            // 8 KiB
    u64*   mst   = (u64*)(ws + 6828032);            // 8 KiB
    int*   mstcnt = (int*)(ws + 6836224);
    int*   pairs  = (int*)(ws + 6840320);           // 8 KiB

    k_init<<<4, 256, 0, stream>>>(cnt, comp, best, mstcnt);
    k_fill<<<EN / 256, 256, 0, stream>>>(dst, cnt, slots);
    k_finish<<<BN / 128, 128, 0, stream>>>(slots, cnt, dinv);

    k_mm8<<<BN / MMR, HD, 0, stream>>>(mu, W1, nullptr, xw, DIN);
    k_gather<<<BN, HD, 0, stream>>>(xw, b1, src, slots, cnt, dinv, h1);
    k_mm8<<<BN / MMR, HD, 0, stream>>>(h1, W2, nullptr, xw, HD);
    k_gather<<<BN, HD, 0, stream>>>(xw, b2, src, slots, cnt, dinv, h2);

    k_mmAC<<<BN / MMR, HD, 0, stream>>>(h2, Ws1, bs1, Aa, Cc);

    k_scores<<<dim3(16, 16), 256, 0, stream>>>(Aa, Cc, Ws2, bs2, S);

    for (int r = 0; r < 10; r++) {
        k_best<<<BN / 4, 256, 0, stream>>>(S, comp, best, mstcnt);
        k_merge<<<1, 1024, 0, stream>>>(comp, best, mst, mstcnt, out, pairs);
    }

    k_gamma<<<BN - 1, HD, 0, stream>>>(h2, pairs, Wg1, bg1, Wg2, bg2, out);
}